// Round 7
// baseline (249.131 us; speedup 1.0000x reference)
//
#include <hip/hip_runtime.h>
#include <cstddef>

// ---------------------------------------------------------------------------
// GCN forward: 3 x ( h@W bf16 MFMA -> packed-bf16 xw -> CSR segsum+LN(+ReLU) )
// N=50000, E=800000, D: 128 -> 128 -> 128 -> 64.
// R7 change vs R6 (passing): h kept in packed-bf16 everywhere. cvt_feat
// converts feat once; agg128 writes packed-bf16 h; gemm reads bf16 A directly
// (uintx4 -> bit_cast fragment, no in-loop f2bf VALU). agg structure
// unchanged from R6.
// ---------------------------------------------------------------------------

typedef __attribute__((ext_vector_type(8))) short bf16x8;
typedef __attribute__((ext_vector_type(4))) float floatx4;
typedef __attribute__((ext_vector_type(4))) unsigned int uintx4;
typedef __attribute__((ext_vector_type(2))) unsigned int uintx2;

static __device__ __forceinline__ unsigned int f2bf(float f) {
    // round-to-nearest-even f32 -> bf16, returned in low 16 bits
    union { float f; unsigned int u; } v; v.f = f;
    unsigned int u = v.u;
    u += 0x7fffu + ((u >> 16) & 1u);
    return u >> 16;
}
static __device__ __forceinline__ float bf_lo(unsigned int p) {
    union { unsigned int u; float f; } v; v.u = p << 16; return v.f;
}
static __device__ __forceinline__ float bf_hi(unsigned int p) {
    union { unsigned int u; float f; } v; v.u = p & 0xffff0000u; return v.f;
}

// ---- feat fp32 -> packed-bf16 (uint) --------------------------------------
// thread i handles 8 consecutive floats -> one uintx4 store.
__global__ __launch_bounds__(256) void cvt_feat(const float* __restrict__ in,
                                                unsigned int* __restrict__ out,
                                                int n8) {
    int i = blockIdx.x * 256 + threadIdx.x;
    if (i < n8) {
        float4 a = ((const float4*)in)[i * 2];
        float4 b = ((const float4*)in)[i * 2 + 1];
        uintx4 p;
        p.x = (f2bf(a.y) << 16) | f2bf(a.x);
        p.y = (f2bf(a.w) << 16) | f2bf(a.z);
        p.z = (f2bf(b.y) << 16) | f2bf(b.x);
        p.w = (f2bf(b.w) << 16) | f2bf(b.z);
        ((uintx4*)out)[i] = p;
    }
}

// ---- W[k][n] fp32 -> Wt[n][kk] packed bf16 pairs (uint), 3 matrices --------
__global__ __launch_bounds__(256) void cvt_w(const float* __restrict__ W0,
                                             const float* __restrict__ W1,
                                             const float* __restrict__ W2,
                                             unsigned int* __restrict__ Wt) {
    const int m = blockIdx.x >> 4;
    const int slice = blockIdx.x & 15;
    const float* W = (m == 0) ? W0 : (m == 1) ? W1 : W2;
    const int ncols = (m == 2) ? 64 : 128;
    unsigned int* dst = Wt + m * 128 * 64;
    const int total = ncols * 64;
    for (int idx = slice * 256 + threadIdx.x; idx < total; idx += 16 * 256) {
        int kk = idx / ncols;          // 0..63
        int n  = idx - kk * ncols;     // consecutive threads -> consecutive n
        unsigned int lo = f2bf(W[(size_t)(2 * kk) * ncols + n]);
        unsigned int hi = f2bf(W[(size_t)(2 * kk + 1) * ncols + n]);
        dst[(size_t)n * 64 + kk] = (hi << 16) | lo;
    }
}

// ---- bf16 MFMA GEMM: C[M,NCOLS] = A[M,128]bf16 @ W, no LDS ----------------
// A packed-uint bf16 [M][64]; Wt packed-uint transposed [NCOLS][64];
// C packed-uint bf16 [M][NCOLS/2]. 4 waves/block; wave = 16 rows x NCOLS.
template <int NCOLS>
__global__ __launch_bounds__(256) void gemm_mfma(const unsigned int* __restrict__ A,
                                                 const unsigned int* __restrict__ Wt,
                                                 unsigned int* __restrict__ C,
                                                 int M) {
    const int lane = threadIdx.x & 63;
    const int wave = threadIdx.x >> 6;
    const int row0 = blockIdx.x * 64 + wave * 16;
    const int quad = lane >> 4;        // k-group: k = quad*8 + j
    const int mcol = lane & 15;        // A row within tile / C col within tile
    const int arow_idx = row0 + mcol;
    const int aload = (arow_idx < M) ? arow_idx : (M - 1);

    constexpr int NT = NCOLS / 16;
    floatx4 acc[NT];
    #pragma unroll
    for (int t = 0; t < NT; ++t) acc[t] = (floatx4){0.f, 0.f, 0.f, 0.f};

    const unsigned int* arow = A + (size_t)aload * 64 + quad * 4;

    #pragma unroll
    for (int k0 = 0; k0 < 128; k0 += 32) {
        uintx4 ap = *(const uintx4*)(arow + k0 / 2);
        bf16x8 a = __builtin_bit_cast(bf16x8, ap);

        const int koff = (k0 + quad * 8) >> 1;   // uint offset within Wt row
        #pragma unroll
        for (int t = 0; t < NT; ++t) {
            const unsigned int* brow = Wt + (size_t)(t * 16 + mcol) * 64 + koff;
            uintx4 bp = *(const uintx4*)brow;
            bf16x8 b = __builtin_bit_cast(bf16x8, bp);
            acc[t] = __builtin_amdgcn_mfma_f32_16x16x32_bf16(a, b, acc[t], 0, 0, 0);
        }
    }

    // C/D layout: col = lane&15, row = quad*4 + reg  [m89/m91].
    const int rowStride = NCOLS >> 1;  // uints per C row
    #pragma unroll
    for (int t = 0; t < NT; ++t) {
        #pragma unroll
        for (int r = 0; r < 4; ++r) {
            unsigned int mybf = f2bf(acc[t][r]);
            unsigned int pair = __shfl_xor(mybf, 1, 64);
            int orow = row0 + quad * 4 + r;
            if (orow < M && (mcol & 1) == 0) {
                unsigned int packed = (pair << 16) | mybf;
                C[(size_t)orow * rowStride + t * 8 + (mcol >> 1)] = packed;
            }
        }
    }
}

// ---- fused CSR segsum + LN + ReLU, D=128, packed-bf16 out ------------------
// Wave per node; lane = (g, sl): g=edge group (4), sl=feature sub-lane (16).
__global__ __launch_bounds__(256) void agg_ln128(const unsigned int* __restrict__ xw,
                                                 const int* __restrict__ ptr,
                                                 const int* __restrict__ col,
                                                 unsigned int* __restrict__ out,
                                                 int N) {
    const int node = blockIdx.x * 4 + (threadIdx.x >> 6);
    if (node >= N) return;
    const int lane = threadIdx.x & 63;
    const int g  = lane >> 4;
    const int sl = lane & 15;
    const int s = ptr[node];
    const int e = ptr[node + 1];

    float acc[8] = {};
    for (int i = s + g; i < e; i += 4) {
        const int src = col[i];
        uintx4 v = *(const uintx4*)(xw + (size_t)src * 64 + sl * 4);
        acc[0] += bf_lo(v.x); acc[1] += bf_hi(v.x);
        acc[2] += bf_lo(v.y); acc[3] += bf_hi(v.y);
        acc[4] += bf_lo(v.z); acc[5] += bf_hi(v.z);
        acc[6] += bf_lo(v.w); acc[7] += bf_hi(v.w);
    }
    #pragma unroll
    for (int j = 0; j < 8; ++j) {
        acc[j] += __shfl_xor(acc[j], 16, 64);
        acc[j] += __shfl_xor(acc[j], 32, 64);
    }
    float s1 = 0.f, s2 = 0.f;
    #pragma unroll
    for (int j = 0; j < 8; ++j) { s1 += acc[j]; s2 += acc[j] * acc[j]; }
    #pragma unroll
    for (int m = 8; m >= 1; m >>= 1) {
        s1 += __shfl_xor(s1, m, 64);
        s2 += __shfl_xor(s2, m, 64);
    }
    const float mean = s1 * (1.0f / 128.0f);
    const float var  = s2 * (1.0f / 128.0f) - mean * mean;
    const float inv  = rsqrtf(var + 1e-5f);

    if (g == 0) {
        float o[8];
        #pragma unroll
        for (int j = 0; j < 8; ++j)
            o[j] = fmaxf((acc[j] - mean) * inv, 0.f);   // ReLU always (layers 0,1)
        uintx4 p;
        p.x = (f2bf(o[1]) << 16) | f2bf(o[0]);
        p.y = (f2bf(o[3]) << 16) | f2bf(o[2]);
        p.z = (f2bf(o[5]) << 16) | f2bf(o[4]);
        p.w = (f2bf(o[7]) << 16) | f2bf(o[6]);
        *(uintx4*)(out + (size_t)node * 64 + sl * 4) = p;
    }
}

// ---- same, D=64, fp32 out (final layer, no ReLU) ---------------------------
__global__ __launch_bounds__(256) void agg_ln64(const unsigned int* __restrict__ xw,
                                                const int* __restrict__ ptr,
                                                const int* __restrict__ col,
                                                float* __restrict__ out, int N) {
    const int node = blockIdx.x * 4 + (threadIdx.x >> 6);
    if (node >= N) return;
    const int lane = threadIdx.x & 63;
    const int g  = lane >> 4;
    const int sl = lane & 15;
    const int s = ptr[node];
    const int e = ptr[node + 1];

    float acc[4] = {};
    for (int i = s + g; i < e; i += 4) {
        const int src = col[i];
        uintx2 v = *(const uintx2*)(xw + (size_t)src * 32 + sl * 2);
        acc[0] += bf_lo(v.x); acc[1] += bf_hi(v.x);
        acc[2] += bf_lo(v.y); acc[3] += bf_hi(v.y);
    }
    #pragma unroll
    for (int j = 0; j < 4; ++j) {
        acc[j] += __shfl_xor(acc[j], 16, 64);
        acc[j] += __shfl_xor(acc[j], 32, 64);
    }
    float s1 = 0.f, s2 = 0.f;
    #pragma unroll
    for (int j = 0; j < 4; ++j) { s1 += acc[j]; s2 += acc[j] * acc[j]; }
    #pragma unroll
    for (int m = 8; m >= 1; m >>= 1) {
        s1 += __shfl_xor(s1, m, 64);
        s2 += __shfl_xor(s2, m, 64);
    }
    const float mean = s1 * (1.0f / 64.0f);
    const float var  = s2 * (1.0f / 64.0f) - mean * mean;
    const float inv  = rsqrtf(var + 1e-5f);

    if (g == 0) {
        float4 o;
        o.x = (acc[0] - mean) * inv;
        o.y = (acc[1] - mean) * inv;
        o.z = (acc[2] - mean) * inv;
        o.w = (acc[3] - mean) * inv;
        *(float4*)(out + (size_t)node * 64 + sl * 4) = o;
    }
}

extern "C" void kernel_launch(void* const* d_in, const int* in_sizes, int n_in,
                              void* d_out, int out_size, void* d_ws, size_t ws_size,
                              hipStream_t stream) {
    const float* feat = (const float*)d_in[0];   // [N,128]
    const float* W0   = (const float*)d_in[1];   // [128,128]
    const float* W1   = (const float*)d_in[2];   // [128,128]
    const float* W2   = (const float*)d_in[3];   // [128,64]
    const int*   ptr  = (const int*)d_in[4];     // [N+1]
    const int*   col  = (const int*)d_in[5];     // [E]
    // d_in[6] = edge_rows, unused (CSR ptr encodes the same segments)

    const int N = in_sizes[4] - 1;               // 50000

    unsigned int* xwp = (unsigned int*)d_ws;                 // [N,64] uint (bf16x2)
    unsigned int* hb  = xwp + (size_t)N * 64;                // [N,64] uint (bf16x2)
    unsigned int* fb  = hb + (size_t)N * 64;                 // [N,64] uint (bf16 feat)
    unsigned int* WtP = fb + (size_t)N * 64;                 // 3 x [128,64] uint
    float*        out = (float*)d_out;                       // [N,64]

    const int gemmBlocks = (N + 63) / 64;        // 782
    const int aggBlocks  = (N + 3) / 4;          // 12500

    cvt_feat<<<(N * 16 + 255) / 256, 256, 0, stream>>>(feat, fb, N * 16);
    cvt_w<<<48, 256, 0, stream>>>(W0, W1, W2, WtP);

    // Layer 0
    gemm_mfma<128><<<gemmBlocks, 256, 0, stream>>>(fb, WtP, xwp, N);
    agg_ln128<<<aggBlocks, 256, 0, stream>>>(xwp, ptr, col, hb, N);
    // Layer 1
    gemm_mfma<128><<<gemmBlocks, 256, 0, stream>>>(hb, WtP + 128 * 64, xwp, N);
    agg_ln128<<<aggBlocks, 256, 0, stream>>>(xwp, ptr, col, hb, N);
    // Layer 2 (D_out=64, no ReLU, fp32 out)
    gemm_mfma<64><<<gemmBlocks, 256, 0, stream>>>(hb, WtP + 2 * 128 * 64, xwp, N);
    agg_ln64<<<aggBlocks, 256, 0, stream>>>(xwp, ptr, col, out, N);
}